// Round 2
// baseline (486.111 us; speedup 1.0000x reference)
//
#include <hip/hip_runtime.h>

// SpMM: out[i,d] = sum_{e: rows[e]==i} vals[e] * x[cols[e], d]
// N=100000 nodes, E=1600000 edges, DIM=32, fp32.
//
// v3: coarse row-bucket binning + LDS accumulation.
//  v2's per-row bins did 8B stores to random cache lines -> WRITE_SIZE 99.4 MB
//  (8x amplification), 115 us. v3 appends edges to 128-row buckets, sub-split
//  8 ways by blockIdx&7 (XCD heuristic) so each bucket tail line is filled by
//  one L2 before eviction -> near-1x write amplification (~13-20 MB).
//  Pass2: one block per bucket, 128x32 fp32 tile in LDS, ds_add_f32 accumulate,
//  coalesced plain store. Writes EVERY output element -> no out memset needed.
//  Rare bucket overflow -> global list -> tiny atomic apply kernel (pass3).
//
//  ws layout:
//   [0      .. 1KB)      : ocount (int) + pad
//   [1KB    .. ~401KB)   : counters, (NB*NSUB) x 64B-padded int
//   [~401KB .. ~1.45MB)  : overflow list, OCAP x int4 {r,c,valbits,_}
//   [~1.45MB.. ~20.7MB)  : buckets, (NB*NSUB) x CAP x int2 {(lrow<<17)|col, valbits}

#define N_NODES 100000
#define N_EDGES 1600000
#define DIM 32

#define RB    128                      // rows per bucket
#define NB    ((N_NODES + RB - 1) / RB)  // 782
#define NSUB  8                        // sub-buckets (XCD heuristic)
#define CAP   384                      // entries per (bucket,sub); mean 256, +8 sigma
#define OCAP  65536                    // overflow capacity

#define OFF_COUNTS   1024
#define OFF_OVER     (OFF_COUNTS + NB * NSUB * 64)          // 1024 + 400384
#define OFF_BUCKETS  (OFF_OVER + OCAP * 16)
#define WS_NEEDED    ((size_t)OFF_BUCKETS + (size_t)NB * NSUB * CAP * 8)

// ---------- fallback: original verified kernel (thread per (edge,dim)) ----------
__global__ __launch_bounds__(256) void spmm_atomic_kernel(
    const int* __restrict__ rows,
    const int* __restrict__ cols,
    const float* __restrict__ vals,
    const float* __restrict__ x,
    float* __restrict__ out)
{
    const long long idx = (long long)blockIdx.x * blockDim.x + threadIdx.x;
    const long long total = (long long)N_EDGES * DIM;
    if (idx >= total) return;

    const int e = (int)(idx >> 5);
    const int d = (int)(idx & 31);

    const int r   = rows[e];
    const int c   = cols[e];
    const float v = vals[e];

    const float xv = x[(long long)c * DIM + d];
    atomicAdd(&out[(long long)r * DIM + d], v * xv);
}

// ---------- pass 1: scatter edges into (bucket, sub) segments ----------
__global__ __launch_bounds__(256) void spmm_scatter_bucket(
    const int* __restrict__ rows,
    const int* __restrict__ cols,
    const float* __restrict__ vals,
    int* __restrict__ ws_counts,     // (NB*NSUB) padded to 16 ints each
    int2* __restrict__ buckets,      // (NB*NSUB) x CAP
    int* __restrict__ ocount,
    int4* __restrict__ overflow)
{
    const int e = blockIdx.x * blockDim.x + threadIdx.x;
    if (e >= N_EDGES) return;

    const int r = rows[e];
    const int c = cols[e];
    const int vb = __float_as_int(vals[e]);

    const int b   = r >> 7;                    // bucket = r / RB
    const int sub = blockIdx.x & (NSUB - 1);   // XCD-locality heuristic
    const int ci  = b * NSUB + sub;

    const int pos = atomicAdd(&ws_counts[ci * 16], 1);
    if (pos < CAP) {
        buckets[ci * CAP + pos] = make_int2(((r & (RB - 1)) << 17) | c, vb);
    } else {
        const int op = atomicAdd(ocount, 1);
        if (op < OCAP) overflow[op] = make_int4(r, c, vb, 0);
    }
}

// ---------- pass 2: per-bucket LDS accumulate + coalesced store ----------
__global__ __launch_bounds__(256) void spmm_bucket_gather(
    const int* __restrict__ ws_counts,
    const int2* __restrict__ buckets,
    const float* __restrict__ x,
    float* __restrict__ out)
{
    __shared__ float acc[RB * DIM];   // 16 KB

    const int tid = threadIdx.x;
    const int b   = blockIdx.x;

    #pragma unroll
    for (int i = tid; i < RB * DIM; i += 256) acc[i] = 0.f;
    __syncthreads();

    const int g = tid >> 5;    // sub-bucket this 32-lane group drains
    const int d = tid & 31;    // dim

    const int ci  = b * NSUB + g;
    const int cnt0 = ws_counts[ci * 16];
    const int cnt  = cnt0 < CAP ? cnt0 : CAP;
    const int2* __restrict__ seg = buckets + (size_t)ci * CAP;

    int k = 0;
    for (; k + 1 < cnt; k += 2) {
        const int2 e0 = seg[k];
        const int2 e1 = seg[k + 1];
        const float x0 = x[(e0.x & 0x1FFFF) * DIM + d];
        const float x1 = x[(e1.x & 0x1FFFF) * DIM + d];
        // non-returning ds_add_f32: iterations independent, loads pipeline
        atomicAdd(&acc[(e0.x >> 17) * DIM + d], __int_as_float(e0.y) * x0);
        atomicAdd(&acc[(e1.x >> 17) * DIM + d], __int_as_float(e1.y) * x1);
    }
    if (k < cnt) {
        const int2 e0 = seg[k];
        const float x0 = x[(e0.x & 0x1FFFF) * DIM + d];
        atomicAdd(&acc[(e0.x >> 17) * DIM + d], __int_as_float(e0.y) * x0);
    }
    __syncthreads();

    // coalesced tile store; covers every output element (no out memset needed)
    const int base = b * (RB * DIM);
    #pragma unroll
    for (int i = tid; i < RB * DIM; i += 256) {
        const int gi = base + i;
        if (gi < N_NODES * DIM) out[gi] = acc[i];
    }
}

// ---------- pass 3: apply rare overflow edges (normally empty) ----------
__global__ __launch_bounds__(256) void spmm_overflow_apply(
    const int* __restrict__ ocount,
    const int4* __restrict__ overflow,
    const float* __restrict__ x,
    float* __restrict__ out)
{
    int n = *ocount;
    if (n > OCAP) n = OCAP;
    const long long total = (long long)n * DIM;
    for (long long idx = (long long)blockIdx.x * blockDim.x + threadIdx.x;
         idx < total; idx += (long long)gridDim.x * blockDim.x) {
        const int e = (int)(idx >> 5);
        const int d = (int)(idx & 31);
        const int4 t = overflow[e];
        atomicAdd(&out[(long long)t.x * DIM + d],
                  __int_as_float(t.z) * x[(long long)t.y * DIM + d]);
    }
}

extern "C" void kernel_launch(void* const* d_in, const int* in_sizes, int n_in,
                              void* d_out, int out_size, void* d_ws, size_t ws_size,
                              hipStream_t stream) {
    const int*   A_rows = (const int*)d_in[0];
    const int*   A_cols = (const int*)d_in[1];
    const float* A_vals = (const float*)d_in[2];
    const float* x      = (const float*)d_in[3];
    float*       out    = (float*)d_out;

    if (d_ws == nullptr || ws_size < WS_NEEDED) {
        // workspace too small: original verified atomic path (needs zeroed out)
        hipMemsetAsync(out, 0, (size_t)out_size * sizeof(float), stream);
        const long long total = (long long)N_EDGES * DIM;
        const int block = 256;
        const long long grid = (total + block - 1) / block;
        spmm_atomic_kernel<<<(dim3)(unsigned)grid, block, 0, stream>>>(
            A_rows, A_cols, A_vals, x, out);
        return;
    }

    char* ws = (char*)d_ws;
    int*  ocount   = (int*)ws;
    int*  counts   = (int*)(ws + OFF_COUNTS);
    int4* overflow = (int4*)(ws + OFF_OVER);
    int2* buckets  = (int2*)(ws + OFF_BUCKETS);

    // zero ocount + counters (~401 KB); out is fully overwritten by pass 2
    hipMemsetAsync(ws, 0, OFF_OVER, stream);

    const int block = 256;
    spmm_scatter_bucket<<<(N_EDGES + block - 1) / block, block, 0, stream>>>(
        A_rows, A_cols, A_vals, counts, buckets, ocount, overflow);

    spmm_bucket_gather<<<NB, block, 0, stream>>>(counts, buckets, x, out);

    spmm_overflow_apply<<<64, block, 0, stream>>>(ocount, overflow, x, out);
}

// Round 3
// 436.438 us; speedup vs baseline: 1.1138x; 1.1138x over previous
//
#include <hip/hip_runtime.h>

// SpMM: out[i,d] = sum_{e: rows[e]==i} vals[e] * x[cols[e], d]
// N=100000 nodes, E=1600000 edges, DIM=32, fp32.
//
// v4: v3's dense-write bucket scatter + high-parallelism gather.
//  v3 post-mortem: gather was latency-bound (782 blocks x 8 streams = 6256
//  serial streams, 22% occupancy, VALUBusy 3.5%). v4: RB=64 (1563 buckets),
//  1024-thread gather blocks = 32 lane-groups, each draining a QUARTER of one
//  sub-bucket -> 50k independent streams of ~32 entries, unroll-4.
//  Scatter/LDS-accumulate/plain-store structure unchanged; out fully written
//  by pass 2 (no out memset). Overflow -> global list -> tiny atomic kernel.
//
//  ws layout (20.3 MB total, <= v3's verified 20.7 MB):
//   [0      .. 1KB)   : ocount (int) + pad
//   [1KB    .. 801KB) : counters, (NB*NSUB) x 64B-padded int
//   [801KB  .. 1.06MB): overflow list, OCAP x int4 {r,c,valbits,_}
//   [1.06MB .. 20.3MB): buckets, (NB*NSUB) x CAP x int2 {(lrow<<17)|col, valbits}

#define N_NODES 100000
#define N_EDGES 1600000
#define DIM 32

#define RB    64                         // rows per bucket
#define NB    ((N_NODES + RB - 1) / RB)  // 1563
#define NSUB  8                          // sub-buckets (XCD heuristic)
#define CAP   192                        // entries per (bucket,sub); mean 128, +5.7 sigma
#define OCAP  16384                      // overflow capacity

#define OFF_COUNTS   1024
#define OFF_OVER     (OFF_COUNTS + NB * NSUB * 64)     // 1024 + 800256
#define OFF_BUCKETS  (OFF_OVER + OCAP * 16)            // + 256KB
#define WS_NEEDED    ((size_t)OFF_BUCKETS + (size_t)NB * NSUB * CAP * 8)

// ---------- fallback: original verified kernel (thread per (edge,dim)) ----------
__global__ __launch_bounds__(256) void spmm_atomic_kernel(
    const int* __restrict__ rows,
    const int* __restrict__ cols,
    const float* __restrict__ vals,
    const float* __restrict__ x,
    float* __restrict__ out)
{
    const long long idx = (long long)blockIdx.x * blockDim.x + threadIdx.x;
    const long long total = (long long)N_EDGES * DIM;
    if (idx >= total) return;

    const int e = (int)(idx >> 5);
    const int d = (int)(idx & 31);

    const int r   = rows[e];
    const int c   = cols[e];
    const float v = vals[e];

    const float xv = x[(long long)c * DIM + d];
    atomicAdd(&out[(long long)r * DIM + d], v * xv);
}

// ---------- pass 1: scatter edges into (bucket, sub) segments ----------
__global__ __launch_bounds__(256) void spmm_scatter_bucket(
    const int* __restrict__ rows,
    const int* __restrict__ cols,
    const float* __restrict__ vals,
    int* __restrict__ ws_counts,     // (NB*NSUB) padded to 16 ints each
    int2* __restrict__ buckets,      // (NB*NSUB) x CAP
    int* __restrict__ ocount,
    int4* __restrict__ overflow)
{
    const int e = blockIdx.x * blockDim.x + threadIdx.x;
    if (e >= N_EDGES) return;

    const int r = rows[e];
    const int c = cols[e];
    const int vb = __float_as_int(vals[e]);

    const int b   = r >> 6;                    // bucket = r / RB
    const int sub = blockIdx.x & (NSUB - 1);   // XCD-locality heuristic
    const int ci  = b * NSUB + sub;

    const int pos = atomicAdd(&ws_counts[ci * 16], 1);
    if (pos < CAP) {
        buckets[ci * CAP + pos] = make_int2(((r & (RB - 1)) << 17) | c, vb);
    } else {
        const int op = atomicAdd(ocount, 1);
        if (op < OCAP) overflow[op] = make_int4(r, c, vb, 0);
    }
}

// ---------- pass 2: per-bucket LDS accumulate + coalesced store ----------
// 1024 threads = 32 lane-groups; group g drains quarter (g&3) of sub (g>>2).
__global__ __launch_bounds__(1024) void spmm_bucket_gather(
    const int* __restrict__ ws_counts,
    const int2* __restrict__ buckets,
    const float* __restrict__ x,
    float* __restrict__ out)
{
    __shared__ float acc[RB * DIM];   // 8 KB

    const int tid = threadIdx.x;
    const int b   = blockIdx.x;

    #pragma unroll
    for (int i = tid; i < RB * DIM; i += 1024) acc[i] = 0.f;
    __syncthreads();

    const int d   = tid & 31;        // dim
    const int g   = tid >> 5;        // lane-group 0..31
    const int sub = g >> 2;          // sub-bucket
    const int q   = g & 3;           // quarter of the segment

    const int ci   = b * NSUB + sub;
    const int cnt0 = ws_counts[ci * 16];
    const int cnt  = cnt0 < CAP ? cnt0 : CAP;
    const int kb   = (cnt * q) >> 2;
    const int ke   = (cnt * (q + 1)) >> 2;
    const int2* __restrict__ seg = buckets + (size_t)ci * CAP;

    int k = kb;
    for (; k + 3 < ke; k += 4) {
        const int2 e0 = seg[k + 0];
        const int2 e1 = seg[k + 1];
        const int2 e2 = seg[k + 2];
        const int2 e3 = seg[k + 3];
        const float x0 = x[(e0.x & 0x1FFFF) * DIM + d];
        const float x1 = x[(e1.x & 0x1FFFF) * DIM + d];
        const float x2 = x[(e2.x & 0x1FFFF) * DIM + d];
        const float x3 = x[(e3.x & 0x1FFFF) * DIM + d];
        // non-returning ds_add_f32; iterations independent -> loads pipeline
        atomicAdd(&acc[(e0.x >> 17) * DIM + d], __int_as_float(e0.y) * x0);
        atomicAdd(&acc[(e1.x >> 17) * DIM + d], __int_as_float(e1.y) * x1);
        atomicAdd(&acc[(e2.x >> 17) * DIM + d], __int_as_float(e2.y) * x2);
        atomicAdd(&acc[(e3.x >> 17) * DIM + d], __int_as_float(e3.y) * x3);
    }
    for (; k < ke; ++k) {
        const int2 e0 = seg[k];
        const float x0 = x[(e0.x & 0x1FFFF) * DIM + d];
        atomicAdd(&acc[(e0.x >> 17) * DIM + d], __int_as_float(e0.y) * x0);
    }
    __syncthreads();

    // coalesced tile store; covers every output element (no out memset needed)
    const int base = b * (RB * DIM);
    #pragma unroll
    for (int i = tid; i < RB * DIM; i += 1024) {
        const int gi = base + i;
        if (gi < N_NODES * DIM) out[gi] = acc[i];
    }
}

// ---------- pass 3: apply rare overflow edges (normally empty) ----------
__global__ __launch_bounds__(256) void spmm_overflow_apply(
    const int* __restrict__ ocount,
    const int4* __restrict__ overflow,
    const float* __restrict__ x,
    float* __restrict__ out)
{
    int n = *ocount;
    if (n > OCAP) n = OCAP;
    const long long total = (long long)n * DIM;
    for (long long idx = (long long)blockIdx.x * blockDim.x + threadIdx.x;
         idx < total; idx += (long long)gridDim.x * blockDim.x) {
        const int e = (int)(idx >> 5);
        const int d = (int)(idx & 31);
        const int4 t = overflow[e];
        atomicAdd(&out[(long long)t.x * DIM + d],
                  __int_as_float(t.z) * x[(long long)t.y * DIM + d]);
    }
}

extern "C" void kernel_launch(void* const* d_in, const int* in_sizes, int n_in,
                              void* d_out, int out_size, void* d_ws, size_t ws_size,
                              hipStream_t stream) {
    const int*   A_rows = (const int*)d_in[0];
    const int*   A_cols = (const int*)d_in[1];
    const float* A_vals = (const float*)d_in[2];
    const float* x      = (const float*)d_in[3];
    float*       out    = (float*)d_out;

    if (d_ws == nullptr || ws_size < WS_NEEDED) {
        // workspace too small: original verified atomic path (needs zeroed out)
        hipMemsetAsync(out, 0, (size_t)out_size * sizeof(float), stream);
        const long long total = (long long)N_EDGES * DIM;
        const int block = 256;
        const long long grid = (total + block - 1) / block;
        spmm_atomic_kernel<<<(dim3)(unsigned)grid, block, 0, stream>>>(
            A_rows, A_cols, A_vals, x, out);
        return;
    }

    char* ws = (char*)d_ws;
    int*  ocount   = (int*)ws;
    int*  counts   = (int*)(ws + OFF_COUNTS);
    int4* overflow = (int4*)(ws + OFF_OVER);
    int2* buckets  = (int2*)(ws + OFF_BUCKETS);

    // zero ocount + counters (~801 KB); out is fully overwritten by pass 2
    hipMemsetAsync(ws, 0, OFF_OVER, stream);

    const int block = 256;
    spmm_scatter_bucket<<<(N_EDGES + block - 1) / block, block, 0, stream>>>(
        A_rows, A_cols, A_vals, counts, buckets, ocount, overflow);

    spmm_bucket_gather<<<NB, 1024, 0, stream>>>(counts, buckets, x, out);

    spmm_overflow_apply<<<64, block, 0, stream>>>(ocount, overflow, x, out);
}

// Round 4
// 194.513 us; speedup vs baseline: 2.4991x; 2.2437x over previous
//
#include <hip/hip_runtime.h>

// SpMM: out[i,d] = sum_{e: rows[e]==i} vals[e] * x[cols[e], d]
// N=100000 nodes, E=1600000 edges, DIM=32, fp32.
//
// v5: dense-write bucket scatter + in-bucket counting sort + register gather.
//  v4 post-mortem: LDS-atomic gather stalled at 300us with VALUBusy 4% /
//  HBM 4% despite 76% occupancy -> the 1.6M LDS fp32 atomicAdds (and their
//  lgkm serialization) were the stall, not the load chain; v2's register
//  gather did the identical x-gather traffic in ~40us. v5 keeps the dense
//  scatter (write-amp fix, v3) and restores register accumulation (v2) by
//  sorting each 64-row bucket by row in a tiny LDS counting-sort pass:
//    pass1 scatter:  edges -> (bucket,sub) segments, dense tail writes
//    pass2 sort:     per bucket: LDS histogram (int ds_add) -> 64-scan ->
//                    in-place re-scatter so each row's (col,val) entries are
//                    contiguous; emit rowinfo[r]={start,cnt}
//    pass3 gather:   one 32-lane group per row, sequential entry reads,
//                    random coalesced x loads, register fmaf, plain store
//                    (writes every output element -> no out memset)
//    pass4 overflow: rare bucket-CAP overflow via global atomics
//
//  ws layout (21.1 MB; v2 verified ws >= 26 MB):
//   [0        .. 1KB)      : ocount
//   [1KB      .. 801KB)    : counters, (NB*NSUB) x 64B-padded int
//   [801KB    .. 1.06MB)   : overflow list, OCAP x int4 {r,c,valbits,_}
//   [1.06MB   .. 1.86MB)   : rowinfo, N x int2 {start, cnt}
//   [1.86MB   .. 21.1MB)   : buckets, NB x 1536 x int2 (sorted in place)

#define N_NODES 100000
#define N_EDGES 1600000
#define DIM 32

#define RB    64                         // rows per bucket
#define NB    ((N_NODES + RB - 1) / RB)  // 1563
#define NSUB  8                          // sub-buckets (XCD heuristic)
#define CAP   192                        // per (bucket,sub); mean 128, +5.7 sigma
#define BTOT  (NSUB * CAP)               // 1536 entries per bucket
#define OCAP  16384

#define OFF_COUNTS   1024
#define OFF_OVER     (OFF_COUNTS + NB * NSUB * 64)     // 1024 + 800256
#define OFF_ROWINFO  (OFF_OVER + OCAP * 16)
#define OFF_BUCKETS  (OFF_ROWINFO + N_NODES * 8)
#define WS_NEEDED    ((size_t)OFF_BUCKETS + (size_t)NB * BTOT * 8)  // ~21.1 MB

// ---------- fallback: original verified kernel (thread per (edge,dim)) ----------
__global__ __launch_bounds__(256) void spmm_atomic_kernel(
    const int* __restrict__ rows,
    const int* __restrict__ cols,
    const float* __restrict__ vals,
    const float* __restrict__ x,
    float* __restrict__ out)
{
    const long long idx = (long long)blockIdx.x * blockDim.x + threadIdx.x;
    const long long total = (long long)N_EDGES * DIM;
    if (idx >= total) return;

    const int e = (int)(idx >> 5);
    const int d = (int)(idx & 31);

    const int r   = rows[e];
    const int c   = cols[e];
    const float v = vals[e];

    const float xv = x[(long long)c * DIM + d];
    atomicAdd(&out[(long long)r * DIM + d], v * xv);
}

// ---------- pass 1: scatter edges into (bucket, sub) segments ----------
__global__ __launch_bounds__(256) void spmm_scatter_bucket(
    const int* __restrict__ rows,
    const int* __restrict__ cols,
    const float* __restrict__ vals,
    int* __restrict__ ws_counts,     // (NB*NSUB) padded to 16 ints each
    int2* __restrict__ buckets,      // NB x BTOT
    int* __restrict__ ocount,
    int4* __restrict__ overflow)
{
    const int e = blockIdx.x * blockDim.x + threadIdx.x;
    if (e >= N_EDGES) return;

    const int r = rows[e];
    const int c = cols[e];
    const int vb = __float_as_int(vals[e]);

    const int b   = r >> 6;                    // bucket = r / RB
    const int sub = blockIdx.x & (NSUB - 1);   // XCD-locality heuristic
    const int ci  = b * NSUB + sub;

    const int pos = atomicAdd(&ws_counts[ci * 16], 1);
    if (pos < CAP) {
        buckets[(size_t)ci * CAP + pos] = make_int2(((r & (RB - 1)) << 17) | c, vb);
    } else {
        const int op = atomicAdd(ocount, 1);
        if (op < OCAP) overflow[op] = make_int4(r, c, vb, 0);
    }
}

// ---------- pass 2: per-bucket counting sort by local row (in place) ----------
__global__ __launch_bounds__(256) void spmm_bucket_sort(
    const int* __restrict__ ws_counts,
    int2* __restrict__ buckets,
    int2* __restrict__ rowinfo)
{
    __shared__ int2 ent[BTOT];      // 12.3 KB staging of the whole bucket
    __shared__ int  hist[RB];
    __shared__ int  startx[RB];
    __shared__ int  cursor[RB];
    __shared__ int  scnt[NSUB];

    const int b   = blockIdx.x;
    const int tid = threadIdx.x;

    if (tid < NSUB) {
        int c0 = ws_counts[(b * NSUB + tid) * 16];
        scnt[tid] = c0 < CAP ? c0 : CAP;
    }
    if (tid < RB) hist[tid] = 0;
    __syncthreads();

    const int g    = tid >> 5;
    const int lane = tid & 31;
    int base = 0;
    #pragma unroll
    for (int s = 0; s < NSUB; ++s) if (s < g) base += scnt[s];
    const int n = scnt[g];
    const int2* __restrict__ seg = buckets + (size_t)(b * NSUB + g) * CAP;

    // stage entries to LDS + row histogram (int LDS atomics: HW ds_add)
    for (int k = lane; k < n; k += 32) {
        const int2 e = seg[k];
        ent[base + k] = e;
        atomicAdd(&hist[e.x >> 17], 1);
    }
    __syncthreads();

    // exclusive scan over 64 row counts (Hillis-Steele in LDS)
    int myh = 0;
    if (tid < RB) { myh = hist[tid]; startx[tid] = myh; }
    __syncthreads();
    for (int off = 1; off < RB; off <<= 1) {
        int v = 0;
        if (tid < RB) { v = startx[tid]; if (tid >= off) v += startx[tid - off]; }
        __syncthreads();
        if (tid < RB) startx[tid] = v;
        __syncthreads();
    }
    int myexcl = 0;
    if (tid < RB) { myexcl = startx[tid] - myh; cursor[tid] = myexcl; }
    __syncthreads();

    // re-scatter: row-contiguous, written back into this bucket's own slice
    int2* __restrict__ dst = buckets + (size_t)b * BTOT;
    for (int k = lane; k < n; k += 32) {
        const int2 e = ent[base + k];
        const int pos = atomicAdd(&cursor[e.x >> 17], 1);
        dst[pos] = make_int2(e.x & 0x1FFFF, e.y);   // strip lrow: store (col, valbits)
    }

    if (tid < RB) {
        const int r = b * RB + tid;
        if (r < N_NODES) rowinfo[r] = make_int2(b * BTOT + myexcl, myh);
    }
}

// ---------- pass 3: register-accumulating row gather (v2-proven shape) ----------
__global__ __launch_bounds__(256) void spmm_row_gather(
    const int2* __restrict__ rowinfo,
    const int2* __restrict__ sorted,
    const float* __restrict__ x,
    float* __restrict__ out)
{
    const int d = threadIdx.x & 31;
    const int r = (blockIdx.x << 3) + (threadIdx.x >> 5);
    if (r >= N_NODES) return;

    const int2 ri = rowinfo[r];
    const int2* __restrict__ seg = sorted + ri.x;
    const int cnt = ri.y;

    float acc = 0.f;
    int k = 0;
    for (; k + 3 < cnt; k += 4) {
        const int2 e0 = seg[k + 0];
        const int2 e1 = seg[k + 1];
        const int2 e2 = seg[k + 2];
        const int2 e3 = seg[k + 3];
        const float x0 = x[e0.x * DIM + d];
        const float x1 = x[e1.x * DIM + d];
        const float x2 = x[e2.x * DIM + d];
        const float x3 = x[e3.x * DIM + d];
        acc = fmaf(__int_as_float(e0.y), x0, acc);
        acc = fmaf(__int_as_float(e1.y), x1, acc);
        acc = fmaf(__int_as_float(e2.y), x2, acc);
        acc = fmaf(__int_as_float(e3.y), x3, acc);
    }
    for (; k < cnt; ++k) {
        const int2 e0 = seg[k];
        acc = fmaf(__int_as_float(e0.y), x[e0.x * DIM + d], acc);
    }

    out[r * DIM + d] = acc;   // covers every row (cnt==0 -> 0); no out memset
}

// ---------- pass 4: apply rare overflow edges (normally empty) ----------
__global__ __launch_bounds__(256) void spmm_overflow_apply(
    const int* __restrict__ ocount,
    const int4* __restrict__ overflow,
    const float* __restrict__ x,
    float* __restrict__ out)
{
    int n = *ocount;
    if (n > OCAP) n = OCAP;
    const long long total = (long long)n * DIM;
    for (long long idx = (long long)blockIdx.x * blockDim.x + threadIdx.x;
         idx < total; idx += (long long)gridDim.x * blockDim.x) {
        const int e = (int)(idx >> 5);
        const int d = (int)(idx & 31);
        const int4 t = overflow[e];
        atomicAdd(&out[(long long)t.x * DIM + d],
                  __int_as_float(t.z) * x[(long long)t.y * DIM + d]);
    }
}

extern "C" void kernel_launch(void* const* d_in, const int* in_sizes, int n_in,
                              void* d_out, int out_size, void* d_ws, size_t ws_size,
                              hipStream_t stream) {
    const int*   A_rows = (const int*)d_in[0];
    const int*   A_cols = (const int*)d_in[1];
    const float* A_vals = (const float*)d_in[2];
    const float* x      = (const float*)d_in[3];
    float*       out    = (float*)d_out;

    if (d_ws == nullptr || ws_size < WS_NEEDED) {
        // workspace too small: original verified atomic path (needs zeroed out)
        hipMemsetAsync(out, 0, (size_t)out_size * sizeof(float), stream);
        const long long total = (long long)N_EDGES * DIM;
        const int block = 256;
        const long long grid = (total + block - 1) / block;
        spmm_atomic_kernel<<<(dim3)(unsigned)grid, block, 0, stream>>>(
            A_rows, A_cols, A_vals, x, out);
        return;
    }

    char* ws = (char*)d_ws;
    int*  ocount   = (int*)ws;
    int*  counts   = (int*)(ws + OFF_COUNTS);
    int4* overflow = (int4*)(ws + OFF_OVER);
    int2* rowinfo  = (int2*)(ws + OFF_ROWINFO);
    int2* buckets  = (int2*)(ws + OFF_BUCKETS);

    // zero ocount + counters (~0.8 MB); out fully written by pass 3
    hipMemsetAsync(ws, 0, OFF_OVER, stream);

    const int block = 256;
    spmm_scatter_bucket<<<(N_EDGES + block - 1) / block, block, 0, stream>>>(
        A_rows, A_cols, A_vals, counts, buckets, ocount, overflow);

    spmm_bucket_sort<<<NB, block, 0, stream>>>(counts, buckets, rowinfo);

    spmm_row_gather<<<(N_NODES + 7) / 8, block, 0, stream>>>(
        rowinfo, buckets, x, out);

    spmm_overflow_apply<<<64, block, 0, stream>>>(ocount, overflow, x, out);
}